// Round 9
// baseline (619.412 us; speedup 1.0000x reference)
//
#include <hip/hip_runtime.h>
#include <hip/hip_bf16.h>

#define NN 16384
#define MM 512
#define DD 64
#define BK 128
#define BM 32
#define ITERS (NN / BK)    // 128
#define BK2 256
#define ITERS2 (NN / BK2)  // 64

typedef __attribute__((ext_vector_type(8))) short short8;
typedef __attribute__((ext_vector_type(4))) float f32x4;
typedef __attribute__((ext_vector_type(4))) short short4v;
typedef __attribute__((ext_vector_type(4))) unsigned u32x4;

#define SE 2097152.0f                 // 2^21 e-scale: max(e)*SE = 256 < 448
#define INV_SE 4.76837158203125e-07f  // 2^-21

__device__ __forceinline__ short f2bf(float f) {
  union { __hip_bfloat16 b; short s; } u;
  u.b = __float2bfloat16(f);
  return u.s;
}

__device__ __forceinline__ short8 cvt8(f32x4 a, f32x4 b) {
  short8 r;
  r[0] = f2bf(a[0]); r[1] = f2bf(a[1]); r[2] = f2bf(a[2]); r[3] = f2bf(a[3]);
  r[4] = f2bf(b[0]); r[5] = f2bf(b[1]); r[6] = f2bf(b[2]); r[7] = f2bf(b[3]);
  return r;
}

typedef __attribute__((address_space(1))) const unsigned gu32;
typedef __attribute__((address_space(3))) unsigned lu32;
__device__ __forceinline__ void gld16(const void* g, void* l) {
  __builtin_amdgcn_global_load_lds((gu32*)g, (lu32*)l, 16, 0, 0);
}

// ---------------------------------------------------------------------------
// xt[d][n] = in[n][:] @ W[d][:] + b[d].  OFMT 0: bf16 out, 1: fp8 e4m3 out.
template <int OFMT>
__global__ __launch_bounds__(256) void linear_mfma(const float* __restrict__ in,
                                                   const float* __restrict__ W,
                                                   const float* __restrict__ b,
                                                   void* __restrict__ xt_) {
  const int t = threadIdx.x, lane = t & 63, w = t >> 6;
  const int rl = lane & 15, hi = lane >> 4;
  const int r0 = blockIdx.x * 64 + w * 16;
  const float* ap = in + (size_t)(r0 + rl) * DD + hi * 8;

  f32x4 acc[4];
#pragma unroll
  for (int g = 0; g < 4; ++g) {
    const float bias = b[g * 16 + rl];
    acc[g][0] = bias; acc[g][1] = bias; acc[g][2] = bias; acc[g][3] = bias;
  }
#pragma unroll
  for (int kk = 0; kk < DD; kk += 32) {
    const short8 af = cvt8(*(const f32x4*)(ap + kk), *(const f32x4*)(ap + kk + 4));
#pragma unroll
    for (int g = 0; g < 4; ++g) {
      const float* wp = W + (size_t)(g * 16 + rl) * DD + hi * 8 + kk;
      const short8 wf = cvt8(*(const f32x4*)wp, *(const f32x4*)(wp + 4));
      acc[g] = __builtin_amdgcn_mfma_f32_16x16x32_bf16(af, wf, acc[g], 0, 0, 0);
    }
  }
  // C/D layout: col = lane&15, row = (lane>>4)*4 + reg
#pragma unroll
  for (int g = 0; g < 4; ++g) {
    if (OFMT == 0) {
      unsigned short* xt = (unsigned short*)xt_;
      short4v s;
      s[0] = f2bf(acc[g][0]); s[1] = f2bf(acc[g][1]);
      s[2] = f2bf(acc[g][2]); s[3] = f2bf(acc[g][3]);
      *(short4v*)(xt + (size_t)(g * 16 + rl) * NN + r0 + hi * 4) = s;
    } else {
      unsigned char* xt = (unsigned char*)xt_;
      int pk = __builtin_amdgcn_cvt_pk_fp8_f32(acc[g][0], acc[g][1], 0, false);
      pk = __builtin_amdgcn_cvt_pk_fp8_f32(acc[g][2], acc[g][3], pk, true);
      *(unsigned*)(xt + (size_t)(g * 16 + rl) * NN + r0 + hi * 4) = (unsigned)pk;
    }
  }
}

// ---------------------------------------------------------------------------
// GEMM1: h1[n][d] = leaky( sum_k e[n][k] * xt0[d][k] ), bf16 MFMA.
// A (HBM stream): LDS double-buffer, gld16, 512B/row spans, XOR swizzle,
// phase rotation — unchanged from r4/r8.  B (2MB L2-resident xt): moved to
// double-buffered REGISTERS (r2's validated indexing; same logical k-map) —
// LDS drops to 32KB -> 3-4 blocks/CU barrier domains.  e8 side-write hoisted.
// Manual 2x loop body keeps all register-array indices static (rule #20).
__global__ __launch_bounds__(256) void gemm1(const float* __restrict__ e,
                                             const unsigned short* __restrict__ xt,
                                             float* __restrict__ out,
                                             unsigned char* __restrict__ e8) {
  __shared__ float Ab[2][BM * BK];  // 2 x 16 KB
  const int t = threadIdx.x, lane = t & 63, w = t >> 6;
  const int rl = lane & 15, hi = lane >> 4;
  const int wr = w >> 1, wc = w & 1;
  const int r0 = blockIdx.x * BM;
  const int it0 = (blockIdx.x * 37) & (ITERS - 1);

  const unsigned short* bp0 = xt + (size_t)(wc * 32 + rl) * NN + hi * 8;
  const unsigned short* bp1 = xt + (size_t)(wc * 32 + 16 + rl) * NN + hi * 8;

  auto STAGE_A = [&](int buf, int it) {
    const int k0 = ((it0 + it) & (ITERS - 1)) * BK;
#pragma unroll
    for (int j = 0; j < 4; ++j) {
      const int row = w * 8 + j * 2 + (lane >> 5);
      const float* src =
          e + (size_t)(r0 + row) * NN + k0 + (((lane & 31) ^ (row & 7)) << 2);
      gld16(src, &Ab[buf][(w * 8 + j * 2) * BK]);
    }
  };

  short8 bA[8], bB[8];
  auto LOADB = [&](short8* dst, int it) {
    const int k0 = ((it0 + it) & (ITERS - 1)) * BK;
#pragma unroll
    for (int kki = 0; kki < 4; ++kki) {
      dst[kki] = *(const short8*)(bp0 + k0 + kki * 32);
      dst[4 + kki] = *(const short8*)(bp1 + k0 + kki * 32);
    }
  };

  f32x4 acc[2];
  acc[0][0] = acc[0][1] = acc[0][2] = acc[0][3] = 0.f;
  acc[1][0] = acc[1][1] = acc[1][2] = acc[1][3] = 0.f;

#define G1BODY(CUR, BCUR, BNXT, IT)                                            \
  {                                                                            \
    const int k0c = ((it0 + (IT)) & (ITERS - 1)) * BK;                         \
    if ((IT) + 1 < ITERS) {                                                    \
      STAGE_A((CUR) ^ 1, (IT) + 1);                                            \
      LOADB(BNXT, (IT) + 1);                                                   \
      asm volatile("s_waitcnt vmcnt(12)" ::: "memory");                        \
    } else {                                                                   \
      asm volatile("s_waitcnt vmcnt(0)" ::: "memory");                         \
    }                                                                          \
    __builtin_amdgcn_s_barrier();                                              \
    asm volatile("" ::: "memory");                                             \
    {                                                                          \
      const int r = t >> 3, j0 = t & 7;                                        \
      const float* arw = &Ab[CUR][r * BK];                                     \
      u32x4 dw;                                                                \
      _Pragma("unroll") for (int i = 0; i < 4; ++i) {                          \
        const int c = j0 * 4 + i;                                              \
        f32x4 q = *(const f32x4*)&arw[(c ^ (r & 7)) << 2];                     \
        int d2 = __builtin_amdgcn_cvt_pk_fp8_f32(q[0] * SE, q[1] * SE, 0, false); \
        d2 = __builtin_amdgcn_cvt_pk_fp8_f32(q[2] * SE, q[3] * SE, d2, true);  \
        dw[i] = (unsigned)d2;                                                  \
      }                                                                        \
      *(u32x4*)(e8 + (size_t)(r0 + r) * NN + k0c + j0 * 16) = dw;              \
    }                                                                          \
    _Pragma("unroll") for (int kk = 0; kk < BK; kk += 32) {                    \
      const int ca = (kk >> 2) + hi * 2;                                       \
      const int arow = (wr * 16 + rl) * BK;                                    \
      f32x4 a0 = *(const f32x4*)&Ab[CUR][arow + ((ca ^ (rl & 7)) << 2)];       \
      f32x4 a1 = *(const f32x4*)&Ab[CUR][arow + (((ca + 1) ^ (rl & 7)) << 2)]; \
      const short8 af = cvt8(a0, a1);                                          \
      acc[0] = __builtin_amdgcn_mfma_f32_16x16x32_bf16(af, (BCUR)[kk >> 5], acc[0], 0, 0, 0);     \
      acc[1] = __builtin_amdgcn_mfma_f32_16x16x32_bf16(af, (BCUR)[4 + (kk >> 5)], acc[1], 0, 0, 0); \
    }                                                                          \
    asm volatile("" ::: "memory");                                             \
    __builtin_amdgcn_s_barrier();                                              \
  }

  STAGE_A(0, 0);
  LOADB(bA, 0);
#pragma unroll 1
  for (int it = 0; it < ITERS; it += 2) {
    G1BODY(0, bA, bB, it);
    G1BODY(1, bB, bA, it + 1);
  }
#undef G1BODY

#pragma unroll
  for (int g = 0; g < 2; ++g) {
    const int col = wc * 32 + g * 16 + rl;
#pragma unroll
    for (int j = 0; j < 4; ++j) {
      float v = acc[g][j];
      v = (v > 0.f) ? v : 0.01f * v;  // leaky_relu
      out[(size_t)(r0 + wr * 16 + hi * 4 + j) * DD + col] = v;
    }
  }
}

// ---------------------------------------------------------------------------
// GEMM2: h[n][d] = tanh( 2^-21 * sum_k e8[n][k] * xt8[d][k] ), fp8 MFMA.
// Same B-in-registers transform: LDS = A only (16KB) -> ~4 blocks/CU.
__global__ __launch_bounds__(256) void gemm2_fp8(const unsigned char* __restrict__ e8,
                                                 const unsigned char* __restrict__ xt8,
                                                 float* __restrict__ out) {
  __shared__ unsigned char Ab2[2][BM * BK2];  // 2 x 8 KB
  const int t = threadIdx.x, lane = t & 63, w = t >> 6;
  const int rl = lane & 15, hi = lane >> 4;
  const int wr = w >> 1, wc = w & 1;
  const int r0 = blockIdx.x * BM;
  const int it0 = (blockIdx.x * 37) & (ITERS2 - 1);

  const unsigned char* bq0 = xt8 + (size_t)(wc * 32 + rl) * NN + hi * 8;
  const unsigned char* bq1 = xt8 + (size_t)(wc * 32 + 16 + rl) * NN + hi * 8;

  auto STAGE_A = [&](int buf, int it) {
    const int k0 = ((it0 + it) & (ITERS2 - 1)) * BK2;
#pragma unroll
    for (int j = 0; j < 2; ++j) {
      const int row = w * 8 + j * 4 + (lane >> 4);
      const unsigned char* src =
          e8 + (size_t)(r0 + row) * NN + k0 + (((lane & 15) ^ (row & 15)) << 4);
      gld16(src, &Ab2[buf][(w * 8 + j * 4) * BK2]);
    }
  };

  long bA[16], bB[16];
  auto LOADB = [&](long* dst, int it) {
    const int k0 = ((it0 + it) & (ITERS2 - 1)) * BK2;
#pragma unroll
    for (int kki = 0; kki < 8; ++kki) {
      dst[kki] = *(const long*)(bq0 + k0 + kki * 32);
      dst[8 + kki] = *(const long*)(bq1 + k0 + kki * 32);
    }
  };

  f32x4 acc[2];
  acc[0][0] = acc[0][1] = acc[0][2] = acc[0][3] = 0.f;
  acc[1][0] = acc[1][1] = acc[1][2] = acc[1][3] = 0.f;

#define G2BODY(CUR, BCUR, BNXT, IT)                                            \
  {                                                                            \
    if ((IT) + 1 < ITERS2) {                                                   \
      STAGE_A((CUR) ^ 1, (IT) + 1);                                            \
      LOADB(BNXT, (IT) + 1);                                                   \
      asm volatile("s_waitcnt vmcnt(18)" ::: "memory");                        \
    } else {                                                                   \
      asm volatile("s_waitcnt vmcnt(0)" ::: "memory");                         \
    }                                                                          \
    __builtin_amdgcn_s_barrier();                                              \
    asm volatile("" ::: "memory");                                             \
    const unsigned char* arw = &Ab2[CUR][(wr * 16 + rl) * BK2];                \
    _Pragma("unroll") for (int kk = 0; kk < BK2; kk += 32) {                   \
      const int ca = (kk >> 4) + (hi >> 1);                                    \
      const int off = (hi & 1) * 8;                                            \
      const long af = *(const long*)&arw[((ca ^ (rl & 15)) << 4) + off];       \
      acc[0] = __builtin_amdgcn_mfma_f32_16x16x32_fp8_fp8(af, (BCUR)[kk >> 5], acc[0], 0, 0, 0);      \
      acc[1] = __builtin_amdgcn_mfma_f32_16x16x32_fp8_fp8(af, (BCUR)[8 + (kk >> 5)], acc[1], 0, 0, 0); \
    }                                                                          \
    asm volatile("" ::: "memory");                                             \
    __builtin_amdgcn_s_barrier();                                              \
  }

  STAGE_A(0, 0);
  LOADB(bA, 0);
#pragma unroll 1
  for (int it = 0; it < ITERS2; it += 2) {
    G2BODY(0, bA, bB, it);
    G2BODY(1, bB, bA, it + 1);
  }
#undef G2BODY

#pragma unroll
  for (int g = 0; g < 2; ++g) {
    const int col = wc * 32 + g * 16 + rl;
#pragma unroll
    for (int j = 0; j < 4; ++j) {
      float v = tanhf(acc[g][j] * INV_SE);
      out[(size_t)(r0 + wr * 16 + hi * 4 + j) * DD + col] = v;
    }
  }
}

// ---------------------------------------------------------------------------
__global__ __launch_bounds__(256) void a_kernel(const float* __restrict__ h,
                                                const float* __restrict__ w2,
                                                const float* __restrict__ b2,
                                                float* __restrict__ a) {
  const int t = threadIdx.x;
  const int lane = t & 63;
  const int n = blockIdx.x * 4 + (t >> 6);
  float v = h[(size_t)n * DD + lane] * w2[lane];
#pragma unroll
  for (int off = 32; off > 0; off >>= 1) v += __shfl_xor(v, off);
  if (lane == 0) a[n] = v + b2[0];
}

// ---------------------------------------------------------------------------
// Fused row-softmax + attentive pool.  One block per molecule.
__global__ __launch_bounds__(256) void softmax_pool(const float* __restrict__ mnm,
                                                    const float* __restrict__ a,
                                                    const float* __restrict__ h,
                                                    float* __restrict__ wout,
                                                    float* __restrict__ out0) {
  __shared__ float red[256];
  __shared__ int redi[256];
  __shared__ float partial[4][64];
  const int m = blockIdx.x, t = threadIdx.x;
  const size_t base = (size_t)m * NN;
  const f32x4* mnm4 = (const f32x4*)(mnm + base);
  const f32x4* a4 = (const f32x4*)a;
  f32x4* wout4 = (f32x4*)(wout + base);

  f32x4 lg[16];  // member ? a : -3e38
  float mx = -3.0e38f;
  int mn_n = NN, mx_n = -1;
#pragma unroll
  for (int i = 0; i < 16; ++i) {
    const int idx = t + i * 256;
    const f32x4 mv = mnm4[idx];
    const f32x4 av = a4[idx];
    f32x4 v;
#pragma unroll
    for (int j = 0; j < 4; ++j) {
      const bool mem = mv[j] > 0.5f;
      v[j] = mem ? av[j] : -3.0e38f;
      if (mem) {
        const int n = idx * 4 + j;
        mn_n = min(mn_n, n);
        mx_n = max(mx_n, n);
      }
    }
    lg[i] = v;
    mx = fmaxf(mx, fmaxf(fmaxf(v[0], v[1]), fmaxf(v[2], v[3])));
  }
  red[t] = mx; redi[t] = mn_n; __syncthreads();
  for (int s = 128; s > 0; s >>= 1) {
    if (t < s) {
      red[t] = fmaxf(red[t], red[t + s]);
      redi[t] = min(redi[t], redi[t + s]);
    }
    __syncthreads();
  }
  mx = red[0];
  const int ns = redi[0];
  __syncthreads();
  redi[t] = mx_n; __syncthreads();
  for (int s = 128; s > 0; s >>= 1) {
    if (t < s) redi[t] = max(redi[t], redi[t + s]);
    __syncthreads();
  }
  const int ne = redi[0];
  __syncthreads();

  const bool empty = (ne < 0);  // no members: reference -> uniform softmax
  float sm = 0.f;
#pragma unroll
  for (int i = 0; i < 16; ++i) {
    f32x4 v = lg[i];
#pragma unroll
    for (int j = 0; j < 4; ++j)
      v[j] = empty ? 1.0f : ((v[j] > -1.0e38f) ? expf(v[j] - mx) : 0.0f);
    lg[i] = v;
    sm += v[0] + v[1] + v[2] + v[3];
  }
  red[t] = sm; __syncthreads();
  for (int s = 128; s > 0; s >>= 1) {
    if (t < s) red[t] += red[t + s];
    __syncthreads();
  }
  const float inv = 1.0f / red[0];
#pragma unroll
  for (int i = 0; i < 16; ++i) wout4[t + i * 256] = lg[i] * inv;

  // make this block's wout row visible to all its threads, then pool
  __threadfence_block();
  __syncthreads();

  const int s0 = empty ? 0 : ns;
  const int e0 = empty ? NN : ne + 1;
  const int d = t & 63, sub = t >> 6;
  const float* wrow = wout + base;
  float accp = 0.f;
  for (int n = s0 + sub; n < e0; n += 4)
    accp += wrow[n] * h[(size_t)n * DD + d];
  partial[sub][d] = accp;
  __syncthreads();
  if (t < 64)
    out0[m * DD + t] =
        partial[0][t] + partial[1][t] + partial[2][t] + partial[3][t];
}

// ---------------------------------------------------------------------------
extern "C" void kernel_launch(void* const* d_in, const int* in_sizes, int n_in,
                              void* d_out, int out_size, void* d_ws, size_t ws_size,
                              hipStream_t stream) {
  const float* nf  = (const float*)d_in[0];
  const float* e   = (const float*)d_in[1];
  const float* mnm = (const float*)d_in[2];
  const float* W0  = (const float*)d_in[4];
  const float* b0  = (const float*)d_in[5];
  const float* W1  = (const float*)d_in[6];
  const float* b1  = (const float*)d_in[7];
  const float* w2  = (const float*)d_in[8];
  const float* b2  = (const float*)d_in[9];

  char* ws = (char*)d_ws;
  unsigned short* XT0 = (unsigned short*)(ws);                            // 2 MB bf16
  unsigned char*  XT8 = (unsigned char*)(ws + (size_t)2 * 1024 * 1024);   // 1 MB fp8
  float* h1 = (float*)(ws + (size_t)4 * 1024 * 1024);                     // 4 MB
  float* h  = (float*)(ws + (size_t)8 * 1024 * 1024);                     // 4 MB
  float* av = (float*)(ws + (size_t)12 * 1024 * 1024);                    // 64 KB
  unsigned char* e8 = (unsigned char*)(ws + (size_t)16 * 1024 * 1024);    // 256 MB

  float* out0 = (float*)d_out;          // [512][64]
  float* wout = out0 + (size_t)MM * DD; // [512][16384]

  linear_mfma<0><<<256, 256, 0, stream>>>(nf, W0, b0, XT0);
  gemm1<<<512, 256, 0, stream>>>(e, XT0, h1, e8);
  linear_mfma<1><<<256, 256, 0, stream>>>(h1, W1, b1, XT8);
  gemm2_fp8<<<512, 256, 0, stream>>>(e8, XT8, h);
  a_kernel<<<4096, 256, 0, stream>>>(h, w2, b2, av);
  softmax_pool<<<512, 256, 0, stream>>>(mnm, av, h, wout, out0);
}

// Round 10
// 488.617 us; speedup vs baseline: 1.2677x; 1.2677x over previous
//
#include <hip/hip_runtime.h>
#include <hip/hip_bf16.h>

#define NN 16384
#define MM 512
#define DD 64
#define BK 128
#define BM 16
#define ITERS (NN / BK)    // 128
#define BK2 256
#define ITERS2 (NN / BK2)  // 64

typedef __attribute__((ext_vector_type(8))) short short8;
typedef __attribute__((ext_vector_type(4))) float f32x4;
typedef __attribute__((ext_vector_type(4))) short short4v;
typedef __attribute__((ext_vector_type(2))) unsigned u32x2;

#define SE 2097152.0f                 // 2^21 e-scale: max(e)*SE = 256 < 448
#define INV_SE 4.76837158203125e-07f  // 2^-21

__device__ __forceinline__ short f2bf(float f) {
  union { __hip_bfloat16 b; short s; } u;
  u.b = __float2bfloat16(f);
  return u.s;
}

__device__ __forceinline__ short8 cvt8(f32x4 a, f32x4 b) {
  short8 r;
  r[0] = f2bf(a[0]); r[1] = f2bf(a[1]); r[2] = f2bf(a[2]); r[3] = f2bf(a[3]);
  r[4] = f2bf(b[0]); r[5] = f2bf(b[1]); r[6] = f2bf(b[2]); r[7] = f2bf(b[3]);
  return r;
}

typedef __attribute__((address_space(1))) const unsigned gu32;
typedef __attribute__((address_space(3))) unsigned lu32;
__device__ __forceinline__ void gld16(const void* g, void* l) {
  __builtin_amdgcn_global_load_lds((gu32*)g, (lu32*)l, 16, 0, 0);
}

// ---------------------------------------------------------------------------
// xt[d][n] = in[n][:] @ W[d][:] + b[d].  OFMT 0: bf16 out, 1: fp8 e4m3 out.
template <int OFMT>
__global__ __launch_bounds__(256) void linear_mfma(const float* __restrict__ in,
                                                   const float* __restrict__ W,
                                                   const float* __restrict__ b,
                                                   void* __restrict__ xt_) {
  const int t = threadIdx.x, lane = t & 63, w = t >> 6;
  const int rl = lane & 15, hi = lane >> 4;
  const int r0 = blockIdx.x * 64 + w * 16;
  const float* ap = in + (size_t)(r0 + rl) * DD + hi * 8;

  f32x4 acc[4];
#pragma unroll
  for (int g = 0; g < 4; ++g) {
    const float bias = b[g * 16 + rl];
    acc[g][0] = bias; acc[g][1] = bias; acc[g][2] = bias; acc[g][3] = bias;
  }
#pragma unroll
  for (int kk = 0; kk < DD; kk += 32) {
    const short8 af = cvt8(*(const f32x4*)(ap + kk), *(const f32x4*)(ap + kk + 4));
#pragma unroll
    for (int g = 0; g < 4; ++g) {
      const float* wp = W + (size_t)(g * 16 + rl) * DD + hi * 8 + kk;
      const short8 wf = cvt8(*(const f32x4*)wp, *(const f32x4*)(wp + 4));
      acc[g] = __builtin_amdgcn_mfma_f32_16x16x32_bf16(af, wf, acc[g], 0, 0, 0);
    }
  }
  // C/D layout: col = lane&15, row = (lane>>4)*4 + reg
#pragma unroll
  for (int g = 0; g < 4; ++g) {
    if (OFMT == 0) {
      unsigned short* xt = (unsigned short*)xt_;
      short4v s;
      s[0] = f2bf(acc[g][0]); s[1] = f2bf(acc[g][1]);
      s[2] = f2bf(acc[g][2]); s[3] = f2bf(acc[g][3]);
      *(short4v*)(xt + (size_t)(g * 16 + rl) * NN + r0 + hi * 4) = s;
    } else {
      unsigned char* xt = (unsigned char*)xt_;
      int pk = __builtin_amdgcn_cvt_pk_fp8_f32(acc[g][0], acc[g][1], 0, false);
      pk = __builtin_amdgcn_cvt_pk_fp8_f32(acc[g][2], acc[g][3], pk, true);
      *(unsigned*)(xt + (size_t)(g * 16 + rl) * NN + r0 + hi * 4) = (unsigned)pk;
    }
  }
}

// ---------------------------------------------------------------------------
// GEMM1: h1[n][d] = leaky( sum_k e[n][k] * xt0[d][k] ), bf16 MFMA.
// r8 structure with BM=16: LDS = A 2x8K + B 2x16K = 48 KB -> 3 blocks/CU
// barrier domains.  Each wave owns one 16x16 frag (col = w*16+rl, rows 0-15).
// vmcnt(6) = exactly this body's 6 staged loads (loads-only count: also
// fixes the r8 prologue race where the first body left 1 load undrained).
// e8 side-write (fp8(e*2^21)) issued right after barrier, drains under MFMAs.
__global__ __launch_bounds__(256) void gemm1(const float* __restrict__ e,
                                             const unsigned short* __restrict__ xt,
                                             float* __restrict__ out,
                                             unsigned char* __restrict__ e8) {
  __shared__ float Ab[2][BM * BK];           // 2 x 8 KB
  __shared__ unsigned short Bb[2][64 * BK];  // 2 x 16 KB
  const int t = threadIdx.x, lane = t & 63, w = t >> 6;
  const int rl = lane & 15, hi = lane >> 4;
  const int r0 = blockIdx.x * BM;
  const int it0 = (blockIdx.x * 37) & (ITERS - 1);

  auto STAGE = [&](int buf, int it) {
    const int k0 = ((it0 + it) & (ITERS - 1)) * BK;
    // A: 2 instrs/wave, each 2 rows x 512B contiguous (16B chunks swizzled)
#pragma unroll
    for (int j = 0; j < 2; ++j) {
      const int row = w * 4 + j * 2 + (lane >> 5);
      const float* src =
          e + (size_t)(r0 + row) * NN + k0 + (((lane & 31) ^ (row & 7)) << 2);
      gld16(src, &Ab[buf][(w * 4 + j * 2) * BK]);
    }
    // B: 4 instrs/wave, each 4 cols x 256B
#pragma unroll
    for (int j = 0; j < 4; ++j) {
      const int col = w * 16 + j * 4 + (lane >> 4);
      const unsigned short* src =
          xt + (size_t)col * NN + k0 + (((lane & 15) ^ (col & 7)) << 3);
      gld16(src, &Bb[buf][(w * 16 + j * 4) * BK]);
    }
  };

  f32x4 acc;
  acc[0] = acc[1] = acc[2] = acc[3] = 0.f;

  STAGE(0, 0);
#pragma unroll 1
  for (int it = 0; it < ITERS; ++it) {
    const int cur = it & 1;
    const int k0c = ((it0 + it) & (ITERS - 1)) * BK;
    if (it + 1 < ITERS) {
      STAGE(cur ^ 1, it + 1);
      asm volatile("s_waitcnt vmcnt(6)" ::: "memory");
    } else {
      asm volatile("s_waitcnt vmcnt(0)" ::: "memory");
    }
    __builtin_amdgcn_s_barrier();
    asm volatile("" ::: "memory");
    // e8 side-write first: store issues early, drains under the MFMAs.
    {
      const int r = t >> 4, j0 = t & 15;  // row 0-15, 8 bytes each
      const float* arw = &Ab[cur][r * BK];
      u32x2 dw;
#pragma unroll
      for (int i = 0; i < 2; ++i) {
        const int c = j0 * 2 + i;
        f32x4 q = *(const f32x4*)&arw[(c ^ (r & 7)) << 2];
        int d2 = __builtin_amdgcn_cvt_pk_fp8_f32(q[0] * SE, q[1] * SE, 0, false);
        d2 = __builtin_amdgcn_cvt_pk_fp8_f32(q[2] * SE, q[3] * SE, d2, true);
        dw[i] = (unsigned)d2;
      }
      *(u32x2*)(e8 + (size_t)(r0 + r) * NN + k0c + j0 * 8) = dw;
    }
#pragma unroll
    for (int kk = 0; kk < BK; kk += 32) {
      const int ca = (kk >> 2) + hi * 2;
      const int arow = rl * BK;
      f32x4 a0 = *(const f32x4*)&Ab[cur][arow + ((ca ^ (rl & 7)) << 2)];
      f32x4 a1 = *(const f32x4*)&Ab[cur][arow + (((ca + 1) ^ (rl & 7)) << 2)];
      const short8 af = cvt8(a0, a1);
      const int cb = (kk >> 3) + hi;
      const int col = w * 16 + rl;
      const short8 bf =
          *(const short8*)&Bb[cur][col * BK + ((cb ^ (rl & 7)) << 3)];
      acc = __builtin_amdgcn_mfma_f32_16x16x32_bf16(af, bf, acc, 0, 0, 0);
    }
    asm volatile("" ::: "memory");
    __builtin_amdgcn_s_barrier();
  }

  // C/D layout: col = lane&15, row = (lane>>4)*4 + reg
  {
    const int col = w * 16 + rl;
#pragma unroll
    for (int j = 0; j < 4; ++j) {
      float v = acc[j];
      v = (v > 0.f) ? v : 0.01f * v;  // leaky_relu
      out[(size_t)(r0 + hi * 4 + j) * DD + col] = v;
    }
  }
}

// ---------------------------------------------------------------------------
// GEMM2: h[n][d] = tanh( 2^-21 * sum_k e8[n][k] * xt8[d][k] ), fp8 MFMA.
// BM=16: LDS = A 2x4K + B 2x16K = 40 KB -> 4 blocks/CU.  vmcnt(5) = this
// body's 5 staged loads.
__global__ __launch_bounds__(256) void gemm2_fp8(const unsigned char* __restrict__ e8,
                                                 const unsigned char* __restrict__ xt8,
                                                 float* __restrict__ out) {
  __shared__ unsigned char Ab2[2][BM * BK2];  // 2 x 4 KB
  __shared__ unsigned char Bb2[2][64 * BK2];  // 2 x 16 KB
  const int t = threadIdx.x, lane = t & 63, w = t >> 6;
  const int rl = lane & 15, hi = lane >> 4;
  const int r0 = blockIdx.x * BM;
  const int it0 = (blockIdx.x * 37) & (ITERS2 - 1);

  auto STAGE = [&](int buf, int it) {
    const int k0 = ((it0 + it) & (ITERS2 - 1)) * BK2;
    // A: 1 instr/wave, 4 rows x 256B
    {
      const int row = w * 4 + (lane >> 4);
      const unsigned char* src =
          e8 + (size_t)(r0 + row) * NN + k0 + (((lane & 15) ^ (row & 15)) << 4);
      gld16(src, &Ab2[buf][w * 4 * BK2]);
    }
    // B: 4 instrs/wave, each 4 cols x 256B
#pragma unroll
    for (int j = 0; j < 4; ++j) {
      const int col = w * 16 + j * 4 + (lane >> 4);
      const unsigned char* src =
          xt8 + (size_t)col * NN + k0 + (((lane & 15) ^ (col & 15)) << 4);
      gld16(src, &Bb2[buf][(w * 16 + j * 4) * BK2]);
    }
  };

  f32x4 acc;
  acc[0] = acc[1] = acc[2] = acc[3] = 0.f;

  STAGE(0, 0);
#pragma unroll 1
  for (int it = 0; it < ITERS2; ++it) {
    const int cur = it & 1;
    if (it + 1 < ITERS2) {
      STAGE(cur ^ 1, it + 1);
      asm volatile("s_waitcnt vmcnt(5)" ::: "memory");
    } else {
      asm volatile("s_waitcnt vmcnt(0)" ::: "memory");
    }
    __builtin_amdgcn_s_barrier();
    asm volatile("" ::: "memory");
    const unsigned char* arw = &Ab2[cur][rl * BK2];
#pragma unroll
    for (int kk = 0; kk < BK2; kk += 32) {
      const int ca = (kk >> 4) + (hi >> 1);  // logical 16B chunk
      const int off = (hi & 1) * 8;
      const long af = *(const long*)&arw[((ca ^ (rl & 15)) << 4) + off];
      const int col = w * 16 + rl;
      const long bf =
          *(const long*)&Bb2[cur][col * BK2 + ((ca ^ (rl & 15)) << 4) + off];
      acc = __builtin_amdgcn_mfma_f32_16x16x32_fp8_fp8(af, bf, acc, 0, 0, 0);
    }
    asm volatile("" ::: "memory");
    __builtin_amdgcn_s_barrier();
  }

  {
    const int col = w * 16 + rl;
#pragma unroll
    for (int j = 0; j < 4; ++j) {
      float v = tanhf(acc[j] * INV_SE);
      out[(size_t)(r0 + hi * 4 + j) * DD + col] = v;
    }
  }
}

// ---------------------------------------------------------------------------
__global__ __launch_bounds__(256) void a_kernel(const float* __restrict__ h,
                                                const float* __restrict__ w2,
                                                const float* __restrict__ b2,
                                                float* __restrict__ a) {
  const int t = threadIdx.x;
  const int lane = t & 63;
  const int n = blockIdx.x * 4 + (t >> 6);
  float v = h[(size_t)n * DD + lane] * w2[lane];
#pragma unroll
  for (int off = 32; off > 0; off >>= 1) v += __shfl_xor(v, off);
  if (lane == 0) a[n] = v + b2[0];
}

// ---------------------------------------------------------------------------
// Fused row-softmax + attentive pool.  One block per molecule.
__global__ __launch_bounds__(256) void softmax_pool(const float* __restrict__ mnm,
                                                    const float* __restrict__ a,
                                                    const float* __restrict__ h,
                                                    float* __restrict__ wout,
                                                    float* __restrict__ out0) {
  __shared__ float red[256];
  __shared__ int redi[256];
  __shared__ float partial[4][64];
  const int m = blockIdx.x, t = threadIdx.x;
  const size_t base = (size_t)m * NN;
  const f32x4* mnm4 = (const f32x4*)(mnm + base);
  const f32x4* a4 = (const f32x4*)a;
  f32x4* wout4 = (f32x4*)(wout + base);

  f32x4 lg[16];  // member ? a : -3e38
  float mx = -3.0e38f;
  int mn_n = NN, mx_n = -1;
#pragma unroll
  for (int i = 0; i < 16; ++i) {
    const int idx = t + i * 256;
    const f32x4 mv = mnm4[idx];
    const f32x4 av = a4[idx];
    f32x4 v;
#pragma unroll
    for (int j = 0; j < 4; ++j) {
      const bool mem = mv[j] > 0.5f;
      v[j] = mem ? av[j] : -3.0e38f;
      if (mem) {
        const int n = idx * 4 + j;
        mn_n = min(mn_n, n);
        mx_n = max(mx_n, n);
      }
    }
    lg[i] = v;
    mx = fmaxf(mx, fmaxf(fmaxf(v[0], v[1]), fmaxf(v[2], v[3])));
  }
  red[t] = mx; redi[t] = mn_n; __syncthreads();
  for (int s = 128; s > 0; s >>= 1) {
    if (t < s) {
      red[t] = fmaxf(red[t], red[t + s]);
      redi[t] = min(redi[t], redi[t + s]);
    }
    __syncthreads();
  }
  mx = red[0];
  const int ns = redi[0];
  __syncthreads();
  redi[t] = mx_n; __syncthreads();
  for (int s = 128; s > 0; s >>= 1) {
    if (t < s) redi[t] = max(redi[t], redi[t + s]);
    __syncthreads();
  }
  const int ne = redi[0];
  __syncthreads();

  const bool empty = (ne < 0);  // no members: reference -> uniform softmax
  float sm = 0.f;
#pragma unroll
  for (int i = 0; i < 16; ++i) {
    f32x4 v = lg[i];
#pragma unroll
    for (int j = 0; j < 4; ++j)
      v[j] = empty ? 1.0f : ((v[j] > -1.0e38f) ? expf(v[j] - mx) : 0.0f);
    lg[i] = v;
    sm += v[0] + v[1] + v[2] + v[3];
  }
  red[t] = sm; __syncthreads();
  for (int s = 128; s > 0; s >>= 1) {
    if (t < s) red[t] += red[t + s];
    __syncthreads();
  }
  const float inv = 1.0f / red[0];
#pragma unroll
  for (int i = 0; i < 16; ++i) wout4[t + i * 256] = lg[i] * inv;

  // make this block's wout row visible to all its threads, then pool
  __threadfence_block();
  __syncthreads();

  const int s0 = empty ? 0 : ns;
  const int e0 = empty ? NN : ne + 1;
  const int d = t & 63, sub = t >> 6;
  const float* wrow = wout + base;
  float accp = 0.f;
  for (int n = s0 + sub; n < e0; n += 4)
    accp += wrow[n] * h[(size_t)n * DD + d];
  partial[sub][d] = accp;
  __syncthreads();
  if (t < 64)
    out0[m * DD + t] =
        partial[0][t] + partial[1][t] + partial[2][t] + partial[3][t];
}

// ---------------------------------------------------------------------------
extern "C" void kernel_launch(void* const* d_in, const int* in_sizes, int n_in,
                              void* d_out, int out_size, void* d_ws, size_t ws_size,
                              hipStream_t stream) {
  const float* nf  = (const float*)d_in[0];
  const float* e   = (const float*)d_in[1];
  const float* mnm = (const float*)d_in[2];
  const float* W0  = (const float*)d_in[4];
  const float* b0  = (const float*)d_in[5];
  const float* W1  = (const float*)d_in[6];
  const float* b1  = (const float*)d_in[7];
  const float* w2  = (const float*)d_in[8];
  const float* b2  = (const float*)d_in[9];

  char* ws = (char*)d_ws;
  unsigned short* XT0 = (unsigned short*)(ws);                            // 2 MB bf16
  unsigned char*  XT8 = (unsigned char*)(ws + (size_t)2 * 1024 * 1024);   // 1 MB fp8
  float* h1 = (float*)(ws + (size_t)4 * 1024 * 1024);                     // 4 MB
  float* h  = (float*)(ws + (size_t)8 * 1024 * 1024);                     // 4 MB
  float* av = (float*)(ws + (size_t)12 * 1024 * 1024);                    // 64 KB
  unsigned char* e8 = (unsigned char*)(ws + (size_t)16 * 1024 * 1024);    // 256 MB

  float* out0 = (float*)d_out;          // [512][64]
  float* wout = out0 + (size_t)MM * DD; // [512][16384]

  linear_mfma<0><<<256, 256, 0, stream>>>(nf, W0, b0, XT0);
  gemm1<<<1024, 256, 0, stream>>>(e, XT0, h1, e8);
  linear_mfma<1><<<256, 256, 0, stream>>>(h1, W1, b1, XT8);
  gemm2_fp8<<<1024, 256, 0, stream>>>(e8, XT8, h);
  a_kernel<<<4096, 256, 0, stream>>>(h, w2, b2, av);
  softmax_pool<<<512, 256, 0, stream>>>(mnm, av, h, wout, out0);
}

// Round 12
// 415.648 us; speedup vs baseline: 1.4902x; 1.1756x over previous
//
#include <hip/hip_runtime.h>
#include <hip/hip_bf16.h>

#define NN 16384
#define MM 512
#define DD 64
#define BM 32
#define BK1 64
#define ITERS1 (NN / BK1)  // 256
#define BK2 256
#define ITERS2 (NN / BK2)  // 64

typedef __attribute__((ext_vector_type(8))) short short8;
typedef __attribute__((ext_vector_type(4))) float f32x4;
typedef __attribute__((ext_vector_type(4))) short short4v;
typedef __attribute__((ext_vector_type(2))) unsigned u32x2;

#define SE 2097152.0f                 // 2^21 e-scale: max(e)*SE = 256 < 448
#define INV_SE 4.76837158203125e-07f  // 2^-21

__device__ __forceinline__ short f2bf(float f) {
  union { __hip_bfloat16 b; short s; } u;
  u.b = __float2bfloat16(f);
  return u.s;
}

__device__ __forceinline__ short8 cvt8(f32x4 a, f32x4 b) {
  short8 r;
  r[0] = f2bf(a[0]); r[1] = f2bf(a[1]); r[2] = f2bf(a[2]); r[3] = f2bf(a[3]);
  r[4] = f2bf(b[0]); r[5] = f2bf(b[1]); r[6] = f2bf(b[2]); r[7] = f2bf(b[3]);
  return r;
}

typedef __attribute__((address_space(1))) const unsigned gu32;
typedef __attribute__((address_space(3))) unsigned lu32;
__device__ __forceinline__ void gld16(const void* g, void* l) {
  __builtin_amdgcn_global_load_lds((gu32*)g, (lu32*)l, 16, 0, 0);
}

// ---------------------------------------------------------------------------
// xt[d][n] = in[n][:] @ W[d][:] + b[d].  OFMT 0: bf16 out, 1: fp8 e4m3 out.
template <int OFMT>
__global__ __launch_bounds__(256) void linear_mfma(const float* __restrict__ in,
                                                   const float* __restrict__ W,
                                                   const float* __restrict__ b,
                                                   void* __restrict__ xt_) {
  const int t = threadIdx.x, lane = t & 63, w = t >> 6;
  const int rl = lane & 15, hi = lane >> 4;
  const int r0 = blockIdx.x * 64 + w * 16;
  const float* ap = in + (size_t)(r0 + rl) * DD + hi * 8;

  f32x4 acc[4];
#pragma unroll
  for (int g = 0; g < 4; ++g) {
    const float bias = b[g * 16 + rl];
    acc[g][0] = bias; acc[g][1] = bias; acc[g][2] = bias; acc[g][3] = bias;
  }
#pragma unroll
  for (int kk = 0; kk < DD; kk += 32) {
    const short8 af = cvt8(*(const f32x4*)(ap + kk), *(const f32x4*)(ap + kk + 4));
#pragma unroll
    for (int g = 0; g < 4; ++g) {
      const float* wp = W + (size_t)(g * 16 + rl) * DD + hi * 8 + kk;
      const short8 wf = cvt8(*(const f32x4*)wp, *(const f32x4*)(wp + 4));
      acc[g] = __builtin_amdgcn_mfma_f32_16x16x32_bf16(af, wf, acc[g], 0, 0, 0);
    }
  }
  // C/D layout: col = lane&15, row = (lane>>4)*4 + reg
#pragma unroll
  for (int g = 0; g < 4; ++g) {
    if (OFMT == 0) {
      unsigned short* xt = (unsigned short*)xt_;
      short4v s;
      s[0] = f2bf(acc[g][0]); s[1] = f2bf(acc[g][1]);
      s[2] = f2bf(acc[g][2]); s[3] = f2bf(acc[g][3]);
      *(short4v*)(xt + (size_t)(g * 16 + rl) * NN + r0 + hi * 4) = s;
    } else {
      unsigned char* xt = (unsigned char*)xt_;
      int pk = __builtin_amdgcn_cvt_pk_fp8_f32(acc[g][0], acc[g][1], 0, false);
      pk = __builtin_amdgcn_cvt_pk_fp8_f32(acc[g][2], acc[g][3], pk, true);
      *(unsigned*)(xt + (size_t)(g * 16 + rl) * NN + r0 + hi * 4) = (unsigned)pk;
    }
  }
}

// ---------------------------------------------------------------------------
// GEMM1: h1[n][d] = leaky( sum_k e[n][k] * xt0[d][k] ), bf16 MFMA.
// BM=32, BK1=64: LDS = A 2x8K + B 2x8K = 32 KB -> 5 blocks/CU barrier
// domains (grid stays 512, so B staging traffic is unchanged vs r8 —
// the clean test of the domain lever r10 botched).  A spans 4 rows x 256B
// per instr; same validated XOR chunk swizzle / k-maps re-derived for
// 16-chunk rows.  vmcnt(4) = loads-only safe count (also drains the
// riding e8 store from the previous body, which is long-committed).
// e8 side-write (fp8(e*2^21)) issued right after barrier, drains under MFMAs.
__global__ __launch_bounds__(256) void gemm1(const float* __restrict__ e,
                                             const unsigned short* __restrict__ xt,
                                             float* __restrict__ out,
                                             unsigned char* __restrict__ e8) {
  __shared__ float Ab[2][BM * BK1];           // 2 x 8 KB
  __shared__ unsigned short Bb[2][64 * BK1];  // 2 x 8 KB
  const int t = threadIdx.x, lane = t & 63, w = t >> 6;
  const int rl = lane & 15, hi = lane >> 4;
  const int wr = w >> 1, wc = w & 1;
  const int r0 = blockIdx.x * BM;
  const int it0 = (blockIdx.x * 37) & (ITERS1 - 1);

  auto STAGE = [&](int buf, int it) {
    const int k0 = ((it0 + it) & (ITERS1 - 1)) * BK1;
    // A: 2 instrs/wave, each 4 rows x 256B (16B chunks swizzled by row&7)
#pragma unroll
    for (int j = 0; j < 2; ++j) {
      const int row = w * 8 + j * 4 + (lane >> 4);
      const float* src =
          e + (size_t)(r0 + row) * NN + k0 + (((lane & 15) ^ (row & 7)) << 2);
      gld16(src, &Ab[buf][(w * 8 + j * 4) * BK1]);
    }
    // B: 2 instrs/wave, each 8 cols x 128B
#pragma unroll
    for (int j = 0; j < 2; ++j) {
      const int col = w * 16 + j * 8 + (lane >> 3);
      const unsigned short* src =
          xt + (size_t)col * NN + k0 + (((lane & 7) ^ (col & 7)) << 3);
      gld16(src, &Bb[buf][(w * 16 + j * 8) * BK1]);
    }
  };

  f32x4 acc[2];
  acc[0][0] = acc[0][1] = acc[0][2] = acc[0][3] = 0.f;
  acc[1][0] = acc[1][1] = acc[1][2] = acc[1][3] = 0.f;

  STAGE(0, 0);
#pragma unroll 1
  for (int it = 0; it < ITERS1; ++it) {
    const int cur = it & 1;
    const int k0c = ((it0 + it) & (ITERS1 - 1)) * BK1;
    if (it + 1 < ITERS1) {
      STAGE(cur ^ 1, it + 1);
      asm volatile("s_waitcnt vmcnt(4)" ::: "memory");
    } else {
      asm volatile("s_waitcnt vmcnt(0)" ::: "memory");
    }
    __builtin_amdgcn_s_barrier();
    asm volatile("" ::: "memory");
    // e8 side-write first: store issues early, drains under the MFMAs.
    {
      const int r = t >> 3, j0 = t & 7;  // 32 rows x 8 chunks of 8B
      const float* arw = &Ab[cur][r * BK1];
      u32x2 dw;
#pragma unroll
      for (int i = 0; i < 2; ++i) {
        const int c = j0 * 2 + i;
        f32x4 q = *(const f32x4*)&arw[(c ^ (r & 7)) << 2];
        int d2 = __builtin_amdgcn_cvt_pk_fp8_f32(q[0] * SE, q[1] * SE, 0, false);
        d2 = __builtin_amdgcn_cvt_pk_fp8_f32(q[2] * SE, q[3] * SE, d2, true);
        dw[i] = (unsigned)d2;
      }
      *(u32x2*)(e8 + (size_t)(r0 + r) * NN + k0c + j0 * 8) = dw;
    }
#pragma unroll
    for (int kk = 0; kk < BK1; kk += 32) {
      const int ca = (kk >> 2) + hi * 2;  // {hi*2, 8+hi*2}
      const int arow = (wr * 16 + rl) * BK1;
      f32x4 a0 = *(const f32x4*)&Ab[cur][arow + ((ca ^ (rl & 7)) << 2)];
      f32x4 a1 = *(const f32x4*)&Ab[cur][arow + (((ca + 1) ^ (rl & 7)) << 2)];
      const short8 af = cvt8(a0, a1);
      const int cb = (kk >> 3) + hi;  // {hi, 4+hi}
#pragma unroll
      for (int g = 0; g < 2; ++g) {
        const int col = wc * 32 + g * 16 + rl;
        const short8 bf =
            *(const short8*)&Bb[cur][col * BK1 + ((cb ^ (rl & 7)) << 3)];
        acc[g] = __builtin_amdgcn_mfma_f32_16x16x32_bf16(af, bf, acc[g], 0, 0, 0);
      }
    }
    asm volatile("" ::: "memory");
    __builtin_amdgcn_s_barrier();
  }

  // C/D layout: col = lane&15, row = (lane>>4)*4 + reg
#pragma unroll
  for (int g = 0; g < 2; ++g) {
    const int col = wc * 32 + g * 16 + rl;
#pragma unroll
    for (int j = 0; j < 4; ++j) {
      float v = acc[g][j];
      v = (v > 0.f) ? v : 0.01f * v;  // leaky_relu
      out[(size_t)(r0 + wr * 16 + hi * 4 + j) * DD + col] = v;
    }
  }
}

// ---------------------------------------------------------------------------
// GEMM2: h[n][d] = tanh( 2^-21 * sum_k e8[n][k] * xt8[d][k] ), fp8 MFMA.
// Exact r8 structure (BM=32, BK2=256, vmcnt(6), LDS 48KB, 2 blocks/CU).
// Fused a[n] = h[n][:] @ w2 + b2 in the epilogue (block holds the full
// 32x64 h tile in registers: rl-direction shuffle reduce + cross-wave LDS add).
__global__ __launch_bounds__(256) void gemm2_fp8(const unsigned char* __restrict__ e8,
                                                 const unsigned char* __restrict__ xt8,
                                                 const float* __restrict__ w2,
                                                 const float* __restrict__ b2,
                                                 float* __restrict__ out,
                                                 float* __restrict__ av) {
  __shared__ unsigned char Ab2[2][BM * BK2];  // 2 x 8 KB
  __shared__ unsigned char Bb2[2][64 * BK2];  // 2 x 16 KB
  __shared__ float aacc[2][16];
  const int t = threadIdx.x, lane = t & 63, w = t >> 6;
  const int rl = lane & 15, hi = lane >> 4;
  const int wr = w >> 1, wc = w & 1;
  const int r0 = blockIdx.x * BM;
  const int it0 = (blockIdx.x * 37) & (ITERS2 - 1);

  auto STAGE = [&](int buf, int it) {
    const int k0 = ((it0 + it) & (ITERS2 - 1)) * BK2;
#pragma unroll
    for (int j = 0; j < 2; ++j) {
      const int row = w * 8 + j * 4 + (lane >> 4);
      const unsigned char* src =
          e8 + (size_t)(r0 + row) * NN + k0 + (((lane & 15) ^ (row & 15)) << 4);
      gld16(src, &Ab2[buf][(w * 8 + j * 4) * BK2]);
    }
#pragma unroll
    for (int j = 0; j < 4; ++j) {
      const int col = w * 16 + j * 4 + (lane >> 4);
      const unsigned char* src =
          xt8 + (size_t)col * NN + k0 + (((lane & 15) ^ (col & 15)) << 4);
      gld16(src, &Bb2[buf][(w * 16 + j * 4) * BK2]);
    }
  };

  f32x4 acc[2];
  acc[0][0] = acc[0][1] = acc[0][2] = acc[0][3] = 0.f;
  acc[1][0] = acc[1][1] = acc[1][2] = acc[1][3] = 0.f;

  STAGE(0, 0);
#pragma unroll 1
  for (int it = 0; it < ITERS2; ++it) {
    const int cur = it & 1;
    if (it + 1 < ITERS2) {
      STAGE(cur ^ 1, it + 1);
      asm volatile("s_waitcnt vmcnt(6)" ::: "memory");
    } else {
      asm volatile("s_waitcnt vmcnt(0)" ::: "memory");
    }
    __builtin_amdgcn_s_barrier();
    asm volatile("" ::: "memory");
    const unsigned char* arw = &Ab2[cur][(wr * 16 + rl) * BK2];
#pragma unroll
    for (int kk = 0; kk < BK2; kk += 32) {
      const int ca = (kk >> 4) + (hi >> 1);  // logical 16B chunk
      const int off = (hi & 1) * 8;
      const long af = *(const long*)&arw[((ca ^ (rl & 15)) << 4) + off];
#pragma unroll
      for (int g = 0; g < 2; ++g) {
        const int col = wc * 32 + g * 16 + rl;
        const long bf =
            *(const long*)&Bb2[cur][col * BK2 + ((ca ^ (col & 15)) << 4) + off];
        acc[g] = __builtin_amdgcn_mfma_f32_16x16x32_fp8_fp8(af, bf, acc[g], 0, 0, 0);
      }
    }
    asm volatile("" ::: "memory");
    __builtin_amdgcn_s_barrier();
  }

  // epilogue: h = tanh(acc/2^21); write h; fused a = h @ w2 + b2
  float hv[2][4];
#pragma unroll
  for (int g = 0; g < 2; ++g) {
    const int col = wc * 32 + g * 16 + rl;
#pragma unroll
    for (int j = 0; j < 4; ++j) {
      hv[g][j] = tanhf(acc[g][j] * INV_SE);
      out[(size_t)(r0 + wr * 16 + hi * 4 + j) * DD + col] = hv[g][j];
    }
  }
  const float w2a = w2[wc * 32 + rl], w2b = w2[wc * 32 + 16 + rl];
  float rp[4];
#pragma unroll
  for (int j = 0; j < 4; ++j) rp[j] = hv[0][j] * w2a + hv[1][j] * w2b;
#pragma unroll
  for (int off = 1; off < 16; off <<= 1)
#pragma unroll
    for (int j = 0; j < 4; ++j) rp[j] += __shfl_xor(rp[j], off);
  if (wc == 0 && rl == 0) {
#pragma unroll
    for (int j = 0; j < 4; ++j) aacc[wr][hi * 4 + j] = rp[j];
  }
  __syncthreads();
  if (wc == 1 && rl == 0) {
    const float bb = b2[0];
#pragma unroll
    for (int j = 0; j < 4; ++j)
      av[r0 + wr * 16 + hi * 4 + j] = aacc[wr][hi * 4 + j] + rp[j] + bb;
  }
}

// ---------------------------------------------------------------------------
// Fused row-softmax + attentive pool.  One block per molecule.
__global__ __launch_bounds__(256) void softmax_pool(const float* __restrict__ mnm,
                                                    const float* __restrict__ a,
                                                    const float* __restrict__ h,
                                                    float* __restrict__ wout,
                                                    float* __restrict__ out0) {
  __shared__ float red[256];
  __shared__ int redi[256];
  __shared__ float partial[4][64];
  const int m = blockIdx.x, t = threadIdx.x;
  const size_t base = (size_t)m * NN;
  const f32x4* mnm4 = (const f32x4*)(mnm + base);
  const f32x4* a4 = (const f32x4*)a;
  f32x4* wout4 = (f32x4*)(wout + base);

  f32x4 lg[16];  // member ? a : -3e38
  float mx = -3.0e38f;
  int mn_n = NN, mx_n = -1;
#pragma unroll
  for (int i = 0; i < 16; ++i) {
    const int idx = t + i * 256;
    const f32x4 mv = mnm4[idx];
    const f32x4 av = a4[idx];
    f32x4 v;
#pragma unroll
    for (int j = 0; j < 4; ++j) {
      const bool mem = mv[j] > 0.5f;
      v[j] = mem ? av[j] : -3.0e38f;
      if (mem) {
        const int n = idx * 4 + j;
        mn_n = min(mn_n, n);
        mx_n = max(mx_n, n);
      }
    }
    lg[i] = v;
    mx = fmaxf(mx, fmaxf(fmaxf(v[0], v[1]), fmaxf(v[2], v[3])));
  }
  red[t] = mx; redi[t] = mn_n; __syncthreads();
  for (int s = 128; s > 0; s >>= 1) {
    if (t < s) {
      red[t] = fmaxf(red[t], red[t + s]);
      redi[t] = min(redi[t], redi[t + s]);
    }
    __syncthreads();
  }
  mx = red[0];
  const int ns = redi[0];
  __syncthreads();
  redi[t] = mx_n; __syncthreads();
  for (int s = 128; s > 0; s >>= 1) {
    if (t < s) redi[t] = max(redi[t], redi[t + s]);
    __syncthreads();
  }
  const int ne = redi[0];
  __syncthreads();

  const bool empty = (ne < 0);  // no members: reference -> uniform softmax
  float sm = 0.f;
#pragma unroll
  for (int i = 0; i < 16; ++i) {
    f32x4 v = lg[i];
#pragma unroll
    for (int j = 0; j < 4; ++j)
      v[j] = empty ? 1.0f : ((v[j] > -1.0e38f) ? expf(v[j] - mx) : 0.0f);
    lg[i] = v;
    sm += v[0] + v[1] + v[2] + v[3];
  }
  red[t] = sm; __syncthreads();
  for (int s = 128; s > 0; s >>= 1) {
    if (t < s) red[t] += red[t + s];
    __syncthreads();
  }
  const float inv = 1.0f / red[0];
#pragma unroll
  for (int i = 0; i < 16; ++i) wout4[t + i * 256] = lg[i] * inv;

  // make this block's wout row visible to all its threads, then pool
  __threadfence_block();
  __syncthreads();

  const int s0 = empty ? 0 : ns;
  const int e0 = empty ? NN : ne + 1;
  const int d = t & 63, sub = t >> 6;
  const float* wrow = wout + base;
  float accp = 0.f;
  for (int n = s0 + sub; n < e0; n += 4)
    accp += wrow[n] * h[(size_t)n * DD + d];
  partial[sub][d] = accp;
  __syncthreads();
  if (t < 64)
    out0[m * DD + t] =
        partial[0][t] + partial[1][t] + partial[2][t] + partial[3][t];
}

// ---------------------------------------------------------------------------
extern "C" void kernel_launch(void* const* d_in, const int* in_sizes, int n_in,
                              void* d_out, int out_size, void* d_ws, size_t ws_size,
                              hipStream_t stream) {
  const float* nf  = (const float*)d_in[0];
  const float* e   = (const float*)d_in[1];
  const float* mnm = (const float*)d_in[2];
  const float* W0  = (const float*)d_in[4];
  const float* b0  = (const float*)d_in[5];
  const float* W1  = (const float*)d_in[6];
  const float* b1  = (const float*)d_in[7];
  const float* w2  = (const float*)d_in[8];
  const float* b2  = (const float*)d_in[9];

  char* ws = (char*)d_ws;
  unsigned short* XT0 = (unsigned short*)(ws);                            // 2 MB bf16
  unsigned char*  XT8 = (unsigned char*)(ws + (size_t)2 * 1024 * 1024);   // 1 MB fp8
  float* h1 = (float*)(ws + (size_t)4 * 1024 * 1024);                     // 4 MB
  float* h  = (float*)(ws + (size_t)8 * 1024 * 1024);                     // 4 MB
  float* av = (float*)(ws + (size_t)12 * 1024 * 1024);                    // 64 KB
  unsigned char* e8 = (unsigned char*)(ws + (size_t)16 * 1024 * 1024);    // 256 MB

  float* out0 = (float*)d_out;          // [512][64]
  float* wout = out0 + (size_t)MM * DD; // [512][16384]

  linear_mfma<0><<<256, 256, 0, stream>>>(nf, W0, b0, XT0);
  gemm1<<<512, 256, 0, stream>>>(e, XT0, h1, e8);
  linear_mfma<1><<<256, 256, 0, stream>>>(h1, W1, b1, XT8);
  gemm2_fp8<<<512, 256, 0, stream>>>(e8, XT8, w2, b2, h, av);
  softmax_pool<<<512, 256, 0, stream>>>(mnm, av, h, wout, out0);
}

// Round 13
// 379.722 us; speedup vs baseline: 1.6312x; 1.0946x over previous
//
#include <hip/hip_runtime.h>
#include <hip/hip_bf16.h>

#define NN 16384
#define MM 512
#define DD 64
#define BK 128
#define BM 32
#define ITERS (NN / BK)    // 128
#define BK2 256
#define ITERS2 (NN / BK2)  // 64

typedef __attribute__((ext_vector_type(8))) short short8;
typedef __attribute__((ext_vector_type(4))) float f32x4;
typedef __attribute__((ext_vector_type(4))) short short4v;
typedef __attribute__((ext_vector_type(4))) unsigned u32x4;

#define SE 2097152.0f                 // 2^21 e-scale: max(e)*SE = 256 < 448
#define INV_SE 4.76837158203125e-07f  // 2^-21

__device__ __forceinline__ short f2bf(float f) {
  union { __hip_bfloat16 b; short s; } u;
  u.b = __float2bfloat16(f);
  return u.s;
}

__device__ __forceinline__ short8 cvt8(f32x4 a, f32x4 b) {
  short8 r;
  r[0] = f2bf(a[0]); r[1] = f2bf(a[1]); r[2] = f2bf(a[2]); r[3] = f2bf(a[3]);
  r[4] = f2bf(b[0]); r[5] = f2bf(b[1]); r[6] = f2bf(b[2]); r[7] = f2bf(b[3]);
  return r;
}

typedef __attribute__((address_space(1))) const unsigned gu32;
typedef __attribute__((address_space(3))) unsigned lu32;
__device__ __forceinline__ void gld16(const void* g, void* l) {
  __builtin_amdgcn_global_load_lds((gu32*)g, (lu32*)l, 16, 0, 0);
}

// ---------------------------------------------------------------------------
// xt[d][n] = in[n][:] @ W[d][:] + b[d].  OFMT 0: bf16 out, 1: fp8 e4m3 out.
template <int OFMT>
__global__ __launch_bounds__(256) void linear_mfma(const float* __restrict__ in,
                                                   const float* __restrict__ W,
                                                   const float* __restrict__ b,
                                                   void* __restrict__ xt_) {
  const int t = threadIdx.x, lane = t & 63, w = t >> 6;
  const int rl = lane & 15, hi = lane >> 4;
  const int r0 = blockIdx.x * 64 + w * 16;
  const float* ap = in + (size_t)(r0 + rl) * DD + hi * 8;

  f32x4 acc[4];
#pragma unroll
  for (int g = 0; g < 4; ++g) {
    const float bias = b[g * 16 + rl];
    acc[g][0] = bias; acc[g][1] = bias; acc[g][2] = bias; acc[g][3] = bias;
  }
#pragma unroll
  for (int kk = 0; kk < DD; kk += 32) {
    const short8 af = cvt8(*(const f32x4*)(ap + kk), *(const f32x4*)(ap + kk + 4));
#pragma unroll
    for (int g = 0; g < 4; ++g) {
      const float* wp = W + (size_t)(g * 16 + rl) * DD + hi * 8 + kk;
      const short8 wf = cvt8(*(const f32x4*)wp, *(const f32x4*)(wp + 4));
      acc[g] = __builtin_amdgcn_mfma_f32_16x16x32_bf16(af, wf, acc[g], 0, 0, 0);
    }
  }
  // C/D layout: col = lane&15, row = (lane>>4)*4 + reg
#pragma unroll
  for (int g = 0; g < 4; ++g) {
    if (OFMT == 0) {
      unsigned short* xt = (unsigned short*)xt_;
      short4v s;
      s[0] = f2bf(acc[g][0]); s[1] = f2bf(acc[g][1]);
      s[2] = f2bf(acc[g][2]); s[3] = f2bf(acc[g][3]);
      *(short4v*)(xt + (size_t)(g * 16 + rl) * NN + r0 + hi * 4) = s;
    } else {
      unsigned char* xt = (unsigned char*)xt_;
      int pk = __builtin_amdgcn_cvt_pk_fp8_f32(acc[g][0], acc[g][1], 0, false);
      pk = __builtin_amdgcn_cvt_pk_fp8_f32(acc[g][2], acc[g][3], pk, true);
      *(unsigned*)(xt + (size_t)(g * 16 + rl) * NN + r0 + hi * 4) = (unsigned)pk;
    }
  }
}

// ---------------------------------------------------------------------------
// GEMM1: h1[n][d] = leaky( sum_k e[n][k] * xt0[d][k] ), bf16 MFMA.
// Exact r8 (384us) structure: BM=32, BK=128, 2 blocks/CU, XOR chunk swizzle,
// phase rotation, e8 side-write hoisted before the MFMAs.
// vmcnt(8) = loads-only count (vs r8's 9): also drains the prev e8-store
// (free, it's a full iteration old) and closes the latent prologue race.
__global__ __launch_bounds__(256) void gemm1(const float* __restrict__ e,
                                             const unsigned short* __restrict__ xt,
                                             float* __restrict__ out,
                                             unsigned char* __restrict__ e8) {
  __shared__ float Ab[2][BM * BK];           // 2 x 16 KB
  __shared__ unsigned short Bb[2][64 * BK];  // 2 x 16 KB
  const int t = threadIdx.x, lane = t & 63, w = t >> 6;
  const int rl = lane & 15, hi = lane >> 4;
  const int wr = w >> 1, wc = w & 1;
  const int r0 = blockIdx.x * BM;
  const int it0 = (blockIdx.x * 37) & (ITERS - 1);

  auto STAGE = [&](int buf, int it) {
    const int k0 = ((it0 + it) & (ITERS - 1)) * BK;
#pragma unroll
    for (int j = 0; j < 4; ++j) {
      const int row = w * 8 + j * 2 + (lane >> 5);
      const float* src =
          e + (size_t)(r0 + row) * NN + k0 + (((lane & 31) ^ (row & 7)) << 2);
      gld16(src, &Ab[buf][(w * 8 + j * 2) * BK]);
    }
#pragma unroll
    for (int j = 0; j < 4; ++j) {
      const int col = w * 16 + j * 4 + (lane >> 4);
      const unsigned short* src =
          xt + (size_t)col * NN + k0 + (((lane & 15) ^ (col & 7)) << 3);
      gld16(src, &Bb[buf][(w * 16 + j * 4) * BK]);
    }
  };

  f32x4 acc[2];
  acc[0][0] = acc[0][1] = acc[0][2] = acc[0][3] = 0.f;
  acc[1][0] = acc[1][1] = acc[1][2] = acc[1][3] = 0.f;

  STAGE(0, 0);
#pragma unroll 1
  for (int it = 0; it < ITERS; ++it) {
    const int cur = it & 1;
    const int k0c = ((it0 + it) & (ITERS - 1)) * BK;
    if (it + 1 < ITERS) {
      STAGE(cur ^ 1, it + 1);
      asm volatile("s_waitcnt vmcnt(8)" ::: "memory");
    } else {
      asm volatile("s_waitcnt vmcnt(0)" ::: "memory");
    }
    __builtin_amdgcn_s_barrier();
    asm volatile("" ::: "memory");
    // e8 side-write first: store issues early, drains under the MFMAs.
    {
      const int r = t >> 3, j0 = t & 7;
      const float* arw = &Ab[cur][r * BK];
      u32x4 dw;
#pragma unroll
      for (int i = 0; i < 4; ++i) {
        const int c = j0 * 4 + i;
        f32x4 q = *(const f32x4*)&arw[(c ^ (r & 7)) << 2];
        int d2 = __builtin_amdgcn_cvt_pk_fp8_f32(q[0] * SE, q[1] * SE, 0, false);
        d2 = __builtin_amdgcn_cvt_pk_fp8_f32(q[2] * SE, q[3] * SE, d2, true);
        dw[i] = (unsigned)d2;
      }
      *(u32x4*)(e8 + (size_t)(r0 + r) * NN + k0c + j0 * 16) = dw;
    }
#pragma unroll
    for (int kk = 0; kk < BK; kk += 32) {
      const int ca = (kk >> 2) + hi * 2;
      const int arow = (wr * 16 + rl) * BK;
      f32x4 a0 = *(const f32x4*)&Ab[cur][arow + ((ca ^ (rl & 7)) << 2)];
      f32x4 a1 = *(const f32x4*)&Ab[cur][arow + (((ca + 1) ^ (rl & 7)) << 2)];
      const short8 af = cvt8(a0, a1);
      const int cb = (kk >> 3) + hi;
#pragma unroll
      for (int g = 0; g < 2; ++g) {
        const int col = wc * 32 + g * 16 + rl;
        const short8 bf =
            *(const short8*)&Bb[cur][col * BK + ((cb ^ (rl & 7)) << 3)];
        acc[g] = __builtin_amdgcn_mfma_f32_16x16x32_bf16(af, bf, acc[g], 0, 0, 0);
      }
    }
    asm volatile("" ::: "memory");
    __builtin_amdgcn_s_barrier();
  }

#pragma unroll
  for (int g = 0; g < 2; ++g) {
    const int col = wc * 32 + g * 16 + rl;
#pragma unroll
    for (int j = 0; j < 4; ++j) {
      float v = acc[g][j];
      v = (v > 0.f) ? v : 0.01f * v;  // leaky_relu
      out[(size_t)(r0 + wr * 16 + hi * 4 + j) * DD + col] = v;
    }
  }
}

// ---------------------------------------------------------------------------
// GEMM2: h[n][d] = tanh( 2^-21 * sum_k e8[n][k] * xt8[d][k] ), fp8 MFMA.
// Exact r8 structure (BM=32, BK2=256, vmcnt(6), LDS 48KB, 2 blocks/CU).
// Fused a[n] = h[n][:] @ w2 + b2 in the epilogue (block holds the full
// 32x64 h tile in registers: rl-direction shuffle reduce + cross-wave LDS add).
__global__ __launch_bounds__(256) void gemm2_fp8(const unsigned char* __restrict__ e8,
                                                 const unsigned char* __restrict__ xt8,
                                                 const float* __restrict__ w2,
                                                 const float* __restrict__ b2,
                                                 float* __restrict__ out,
                                                 float* __restrict__ av) {
  __shared__ unsigned char Ab2[2][BM * BK2];  // 2 x 8 KB
  __shared__ unsigned char Bb2[2][64 * BK2];  // 2 x 16 KB
  __shared__ float aacc[2][16];
  const int t = threadIdx.x, lane = t & 63, w = t >> 6;
  const int rl = lane & 15, hi = lane >> 4;
  const int wr = w >> 1, wc = w & 1;
  const int r0 = blockIdx.x * BM;
  const int it0 = (blockIdx.x * 37) & (ITERS2 - 1);

  auto STAGE = [&](int buf, int it) {
    const int k0 = ((it0 + it) & (ITERS2 - 1)) * BK2;
#pragma unroll
    for (int j = 0; j < 2; ++j) {
      const int row = w * 8 + j * 4 + (lane >> 4);
      const unsigned char* src =
          e8 + (size_t)(r0 + row) * NN + k0 + (((lane & 15) ^ (row & 15)) << 4);
      gld16(src, &Ab2[buf][(w * 8 + j * 4) * BK2]);
    }
#pragma unroll
    for (int j = 0; j < 4; ++j) {
      const int col = w * 16 + j * 4 + (lane >> 4);
      const unsigned char* src =
          xt8 + (size_t)col * NN + k0 + (((lane & 15) ^ (col & 15)) << 4);
      gld16(src, &Bb2[buf][(w * 16 + j * 4) * BK2]);
    }
  };

  f32x4 acc[2];
  acc[0][0] = acc[0][1] = acc[0][2] = acc[0][3] = 0.f;
  acc[1][0] = acc[1][1] = acc[1][2] = acc[1][3] = 0.f;

  STAGE(0, 0);
#pragma unroll 1
  for (int it = 0; it < ITERS2; ++it) {
    const int cur = it & 1;
    if (it + 1 < ITERS2) {
      STAGE(cur ^ 1, it + 1);
      asm volatile("s_waitcnt vmcnt(6)" ::: "memory");
    } else {
      asm volatile("s_waitcnt vmcnt(0)" ::: "memory");
    }
    __builtin_amdgcn_s_barrier();
    asm volatile("" ::: "memory");
    const unsigned char* arw = &Ab2[cur][(wr * 16 + rl) * BK2];
#pragma unroll
    for (int kk = 0; kk < BK2; kk += 32) {
      const int ca = (kk >> 4) + (hi >> 1);  // logical 16B chunk
      const int off = (hi & 1) * 8;
      const long af = *(const long*)&arw[((ca ^ (rl & 15)) << 4) + off];
#pragma unroll
      for (int g = 0; g < 2; ++g) {
        const int col = wc * 32 + g * 16 + rl;
        const long bf =
            *(const long*)&Bb2[cur][col * BK2 + ((ca ^ (col & 15)) << 4) + off];
        acc[g] = __builtin_amdgcn_mfma_f32_16x16x32_fp8_fp8(af, bf, acc[g], 0, 0, 0);
      }
    }
    asm volatile("" ::: "memory");
    __builtin_amdgcn_s_barrier();
  }

  // epilogue: h = tanh(acc/2^21); write h; fused a = h @ w2 + b2
  float hv[2][4];
#pragma unroll
  for (int g = 0; g < 2; ++g) {
    const int col = wc * 32 + g * 16 + rl;
#pragma unroll
    for (int j = 0; j < 4; ++j) {
      hv[g][j] = tanhf(acc[g][j] * INV_SE);
      out[(size_t)(r0 + wr * 16 + hi * 4 + j) * DD + col] = hv[g][j];
    }
  }
  const float w2a = w2[wc * 32 + rl], w2b = w2[wc * 32 + 16 + rl];
  float rp[4];
#pragma unroll
  for (int j = 0; j < 4; ++j) rp[j] = hv[0][j] * w2a + hv[1][j] * w2b;
#pragma unroll
  for (int off = 1; off < 16; off <<= 1)
#pragma unroll
    for (int j = 0; j < 4; ++j) rp[j] += __shfl_xor(rp[j], off);
  if (wc == 0 && rl == 0) {
#pragma unroll
    for (int j = 0; j < 4; ++j) aacc[wr][hi * 4 + j] = rp[j];
  }
  __syncthreads();
  if (wc == 1 && rl == 0) {
    const float bb = b2[0];
#pragma unroll
    for (int j = 0; j < 4; ++j)
      av[r0 + wr * 16 + hi * 4 + j] = aacc[wr][hi * 4 + j] + rp[j] + bb;
  }
}

// ---------------------------------------------------------------------------
// Fused row-softmax + attentive pool.  One block per molecule.
__global__ __launch_bounds__(256) void softmax_pool(const float* __restrict__ mnm,
                                                    const float* __restrict__ a,
                                                    const float* __restrict__ h,
                                                    float* __restrict__ wout,
                                                    float* __restrict__ out0) {
  __shared__ float red[256];
  __shared__ int redi[256];
  __shared__ float partial[4][64];
  const int m = blockIdx.x, t = threadIdx.x;
  const size_t base = (size_t)m * NN;
  const f32x4* mnm4 = (const f32x4*)(mnm + base);
  const f32x4* a4 = (const f32x4*)a;
  f32x4* wout4 = (f32x4*)(wout + base);

  f32x4 lg[16];  // member ? a : -3e38
  float mx = -3.0e38f;
  int mn_n = NN, mx_n = -1;
#pragma unroll
  for (int i = 0; i < 16; ++i) {
    const int idx = t + i * 256;
    const f32x4 mv = mnm4[idx];
    const f32x4 av = a4[idx];
    f32x4 v;
#pragma unroll
    for (int j = 0; j < 4; ++j) {
      const bool mem = mv[j] > 0.5f;
      v[j] = mem ? av[j] : -3.0e38f;
      if (mem) {
        const int n = idx * 4 + j;
        mn_n = min(mn_n, n);
        mx_n = max(mx_n, n);
      }
    }
    lg[i] = v;
    mx = fmaxf(mx, fmaxf(fmaxf(v[0], v[1]), fmaxf(v[2], v[3])));
  }
  red[t] = mx; redi[t] = mn_n; __syncthreads();
  for (int s = 128; s > 0; s >>= 1) {
    if (t < s) {
      red[t] = fmaxf(red[t], red[t + s]);
      redi[t] = min(redi[t], redi[t + s]);
    }
    __syncthreads();
  }
  mx = red[0];
  const int ns = redi[0];
  __syncthreads();
  redi[t] = mx_n; __syncthreads();
  for (int s = 128; s > 0; s >>= 1) {
    if (t < s) redi[t] = max(redi[t], redi[t + s]);
    __syncthreads();
  }
  const int ne = redi[0];
  __syncthreads();

  const bool empty = (ne < 0);  // no members: reference -> uniform softmax
  float sm = 0.f;
#pragma unroll
  for (int i = 0; i < 16; ++i) {
    f32x4 v = lg[i];
#pragma unroll
    for (int j = 0; j < 4; ++j)
      v[j] = empty ? 1.0f : ((v[j] > -1.0e38f) ? expf(v[j] - mx) : 0.0f);
    lg[i] = v;
    sm += v[0] + v[1] + v[2] + v[3];
  }
  red[t] = sm; __syncthreads();
  for (int s = 128; s > 0; s >>= 1) {
    if (t < s) red[t] += red[t + s];
    __syncthreads();
  }
  const float inv = 1.0f / red[0];
#pragma unroll
  for (int i = 0; i < 16; ++i) wout4[t + i * 256] = lg[i] * inv;

  // make this block's wout row visible to all its threads, then pool
  __threadfence_block();
  __syncthreads();

  const int s0 = empty ? 0 : ns;
  const int e0 = empty ? NN : ne + 1;
  const int d = t & 63, sub = t >> 6;
  const float* wrow = wout + base;
  float accp = 0.f;
  for (int n = s0 + sub; n < e0; n += 4)
    accp += wrow[n] * h[(size_t)n * DD + d];
  partial[sub][d] = accp;
  __syncthreads();
  if (t < 64)
    out0[m * DD + t] =
        partial[0][t] + partial[1][t] + partial[2][t] + partial[3][t];
}

// ---------------------------------------------------------------------------
extern "C" void kernel_launch(void* const* d_in, const int* in_sizes, int n_in,
                              void* d_out, int out_size, void* d_ws, size_t ws_size,
                              hipStream_t stream) {
  const float* nf  = (const float*)d_in[0];
  const float* e   = (const float*)d_in[1];
  const float* mnm = (const float*)d_in[2];
  const float* W0  = (const float*)d_in[4];
  const float* b0  = (const float*)d_in[5];
  const float* W1  = (const float*)d_in[6];
  const float* b1  = (const float*)d_in[7];
  const float* w2  = (const float*)d_in[8];
  const float* b2  = (const float*)d_in[9];

  char* ws = (char*)d_ws;
  unsigned short* XT0 = (unsigned short*)(ws);                            // 2 MB bf16
  unsigned char*  XT8 = (unsigned char*)(ws + (size_t)2 * 1024 * 1024);   // 1 MB fp8
  float* h1 = (float*)(ws + (size_t)4 * 1024 * 1024);                     // 4 MB
  float* h  = (float*)(ws + (size_t)8 * 1024 * 1024);                     // 4 MB
  float* av = (float*)(ws + (size_t)12 * 1024 * 1024);                    // 64 KB
  unsigned char* e8 = (unsigned char*)(ws + (size_t)16 * 1024 * 1024);    // 256 MB

  float* out0 = (float*)d_out;          // [512][64]
  float* wout = out0 + (size_t)MM * DD; // [512][16384]

  linear_mfma<0><<<256, 256, 0, stream>>>(nf, W0, b0, XT0);
  gemm1<<<512, 256, 0, stream>>>(e, XT0, h1, e8);
  linear_mfma<1><<<256, 256, 0, stream>>>(h1, W1, b1, XT8);
  gemm2_fp8<<<512, 256, 0, stream>>>(e8, XT8, w2, b2, h, av);
  softmax_pool<<<512, 256, 0, stream>>>(mnm, av, h, wout, out0);
}